// Round 2
// baseline (606.550 us; speedup 1.0000x reference)
//
#include <hip/hip_runtime.h>
#include <hip/hip_bf16.h>
#include <stdint.h>

#define DFEAT 256
#define NPTS  8192

typedef __attribute__((ext_vector_type(8)))  short bf16x8;   // 8 bf16 = 4 VGPRs
typedef __attribute__((ext_vector_type(16))) float f32x16;   // 32x32 C/D
typedef __attribute__((ext_vector_type(4)))  int   int4v;

#define AS1 __attribute__((address_space(1)))
#define AS3 __attribute__((address_space(3)))

__device__ inline void dma16(const void* g, void* l) {
  // async global->LDS, 16B per lane; LDS dest = wave-uniform base + lane*16
  __builtin_amdgcn_global_load_lds((const AS1 uint32_t*)g, (AS3 uint32_t*)l, 16, 0, 0);
}

__device__ inline uint16_t f2bf(float f) {  // RNE fp32->bf16
  union { float f; uint32_t u; } v; v.f = f;
  return (uint16_t)((v.u + 0x7FFFu + ((v.u >> 16) & 1u)) >> 16);
}

// ---------------------------------------------------------------------------
// Fused flash-style mean-shift step. Per m-tile (64 cols) x n-split, loop n:
//   S[n,m] = Xn^T Xm   (A-frags direct from global xtb -> regs; B in regs)
//   P = exp(6S) -> LDS ; CS[m] += colsum(P)
//   O[d,m] += Xn P     (Xn staged in LDS via global_load_lds, overlapped w/ S)
// 2 barriers/iter: top (LDS WAR) and mid (DMA done + Ps visible).
// grid = 128 m-tiles x 4 n-splits; partials merged via fp32 atomics.
// ---------------------------------------------------------------------------
__global__ __launch_bounds__(256, 2) void ms_fused(
    const uint16_t* __restrict__ xb,   // bf16 X  [256][8192]
    const uint16_t* __restrict__ xtb,  // bf16 X^T [8192][256]
    float* __restrict__ num,           // [256][8192] fp32, pre-zeroed
    float* __restrict__ cs)            // [8192] fp32, pre-zeroed
{
  __shared__ __attribute__((aligned(16))) uint16_t Xn [DFEAT*64];   // [d][n] rows 128B, swizzled
  __shared__ __attribute__((aligned(16))) uint16_t Ps [4*64*18];    // [ks][m][16+2 pad]

  const int tid  = threadIdx.x;
  const int w    = tid >> 6;
  const int lane = tid & 63;
  const int l31  = lane & 31;
  const int g    = lane >> 5;
  const int m0   = (blockIdx.x >> 2) * 64;   // m-tile base
  const int q    = blockIdx.x & 3;           // n-split
  const int a_sub = w >> 1;                  // S n-sub (0/1)
  const int b_sub = w & 1;                   // S m-sub (0/1)

  // Xm B-fragments (B[k=d][col=m]): row m of X^T, kept in registers (64 VGPRs)
  bf16x8 Bm[16];
  {
    const uint16_t* mrow = xtb + (size_t)(m0 + 32*b_sub + l31) * DFEAT;
    #pragma unroll
    for (int ks = 0; ks < 16; ++ks)
      Bm[ks] = __builtin_bit_cast(bf16x8, *(const int4v*)(mrow + ks*16 + g*8));
  }

  f32x16 accO[2][2];
  #pragma unroll
  for (int i = 0; i < 2; ++i)
    #pragma unroll
    for (int j = 0; j < 2; ++j)
      #pragma unroll
      for (int r = 0; r < 16; ++r) accO[i][j][r] = 0.0f;
  float csacc = 0.0f;

  // Xn staging lane constants (r-independent thanks to 32r stride)
  const int xn_d0   = tid >> 3;                               // + 32*r
  const int xn_noff = ((tid & 7) ^ ((tid >> 3) & 7)) * 8;     // swizzled chunk

  for (int t = 0; t < 32; ++t) {
    const int n0 = q * 2048 + t * 64;
    __syncthreads();  // prev PV done (Xn + Ps free for overwrite)

    // S A-fragments straight from global (L2/L3-resident): row n, 16B chunks
    bf16x8 Af[16];
    {
      const uint16_t* arow = xtb + (size_t)(n0 + 32*a_sub + l31) * DFEAT;
      #pragma unroll
      for (int ks = 0; ks < 16; ++ks)
        Af[ks] = __builtin_bit_cast(bf16x8, *(const int4v*)(arow + ks*16 + g*8));
    }

    // stage Xn [256][64] async; overlaps with S + exp below.
    // chunk c holds global chunk (c&7)^(d&7) of row d
    #pragma unroll
    for (int r = 0; r < 8; ++r) {
      const uint16_t* gp = xb + (size_t)(xn_d0 + 32*r) * NPTS + n0 + xn_noff;
      dma16(gp, (char*)Xn + (r*256 + tid) * 16);
    }

    // ---- S = Xn^T Xm (wave quadrant), dual chains for ILP ----
    f32x16 s0, s1;
    #pragma unroll
    for (int r = 0; r < 16; ++r) { s0[r] = 0.0f; s1[r] = 0.0f; }
    #pragma unroll
    for (int ks2 = 0; ks2 < 8; ++ks2) {
      s0 = __builtin_amdgcn_mfma_f32_32x32x16_bf16(Af[2*ks2],   Bm[2*ks2],   s0, 0, 0, 0);
      s1 = __builtin_amdgcn_mfma_f32_32x32x16_bf16(Af[2*ks2+1], Bm[2*ks2+1], s1, 0, 0, 0);
    }

    // ---- P = exp(6S); colsum partial; write P to LDS k-slices ----
    {
      const int mloc = 32*b_sub + l31;
      float e[16];
      #pragma unroll
      for (int r = 0; r < 16; ++r) {
        e[r] = __expf(6.0f * (s0[r] + s1[r]));
        csacc += e[r];
      }
      #pragma unroll
      for (int j = 0; j < 8; ++j) {   // reg pairs (2j,2j+1) = consecutive n
        int nn = 32*a_sub + ((2*j) & 3) + 8*((2*j) >> 2) + 4*g;
        uint32_t pk = (uint32_t)f2bf(e[2*j]) | ((uint32_t)f2bf(e[2*j+1]) << 16);
        *(uint32_t*)((char*)Ps + (nn >> 4)*2304 + mloc*36 + (nn & 15)*2) = pk;
      }
    }
    __syncthreads();  // Xn DMA complete + Ps visible (one barrier serves both)

    // ---- O[d,m] += Xn * P  (wave: d-tiles {2w,2w+1}, both m-subs) ----
    #pragma unroll
    for (int ks = 0; ks < 4; ++ks) {
      bf16x8 Bp[2];
      #pragma unroll
      for (int mm = 0; mm < 2; ++mm) {
        const char* base = (const char*)Ps + ks*2304 + (32*mm + l31)*36 + g*16;
        union { uint32_t u[4]; bf16x8 v; } tb;
        tb.u[0] = *(const uint32_t*)(base);
        tb.u[1] = *(const uint32_t*)(base + 4);
        tb.u[2] = *(const uint32_t*)(base + 8);
        tb.u[3] = *(const uint32_t*)(base + 12);
        Bp[mm] = tb.v;
      }
      #pragma unroll
      for (int t2 = 0; t2 < 2; ++t2) {
        const int drow = 32*(2*w + t2) + l31;
        int slot = (2*ks + g) ^ (l31 & 7);  // undo swizzle (d&7 == l31&7)
        bf16x8 A = __builtin_bit_cast(bf16x8,
            *(const int4v*)((const char*)Xn + drow*128 + slot*16));
        accO[t2][0] = __builtin_amdgcn_mfma_f32_32x32x16_bf16(A, Bp[0], accO[t2][0], 0,0,0);
        accO[t2][1] = __builtin_amdgcn_mfma_f32_32x32x16_bf16(A, Bp[1], accO[t2][1], 0,0,0);
      }
    }
  }

  // ---- epilogue: merge partials ----
  csacc += __shfl_xor(csacc, 32, 64);
  if (g == 0) atomicAdd(&cs[m0 + 32*b_sub + l31], csacc);
  #pragma unroll
  for (int t2 = 0; t2 < 2; ++t2)
    #pragma unroll
    for (int mm = 0; mm < 2; ++mm)
      #pragma unroll
      for (int r = 0; r < 16; ++r) {
        int drow = 32*(2*w + t2) + (r & 3) + 8*(r >> 2) + 4*g;
        int mg   = m0 + 32*mm + l31;
        atomicAdd(&num[(size_t)drow * NPTS + mg], accO[t2][mm][r]);
      }
}

// ---------------------------------------------------------------------------
// Combine: mode 1: Y = Num / CS -> d_out slice + bf16 X / X^T for next iter.
//          mode 0: just convert fp32 src -> bf16 X / X^T (initial X).
// ---------------------------------------------------------------------------
__global__ __launch_bounds__(256) void ms_combine(
    const float* __restrict__ src, const float* __restrict__ cs,
    float* __restrict__ yout, uint16_t* __restrict__ xbo, uint16_t* __restrict__ xto,
    const int mode)
{
  __shared__ uint16_t T[64][66];
  const int tid = threadIdx.x;
  const int n0 = blockIdx.x * 64;
  const int d0 = blockIdx.y * 64;
  #pragma unroll
  for (int i = 0; i < 16; ++i) {
    int e  = tid + i*256;
    int dl = e >> 6, nl = e & 63;
    size_t idx = (size_t)(d0 + dl) * NPTS + (n0 + nl);
    float v = src[idx];
    if (mode) { v /= cs[n0 + nl]; yout[idx] = v; }
    uint16_t b = f2bf(v);
    xbo[idx] = b;
    T[dl][nl] = b;
  }
  __syncthreads();
  #pragma unroll
  for (int i = 0; i < 8; ++i) {
    int p  = tid + i*256;
    int nl = p >> 5, dp = p & 31;
    uint32_t pk = (uint32_t)T[2*dp][nl] | ((uint32_t)T[2*dp+1][nl] << 16);
    ((uint32_t*)xto)[(((size_t)(n0 + nl) * DFEAT + d0) >> 1) + dp] = pk;
  }
}

extern "C" void kernel_launch(void* const* d_in, const int* in_sizes, int n_in,
                              void* d_out, int out_size, void* d_ws, size_t ws_size,
                              hipStream_t stream)
{
  (void)in_sizes; (void)n_in; (void)out_size; (void)ws_size;
  const float* X = (const float*)d_in[0];
  float* out = (float*)d_out;
  char* ws = (char*)d_ws;
  // ws layout: [0,4M) bf16 X ; [4M,8M) bf16 X^T ; [8M,16M) Num fp32 ; [16M,+32K) CS fp32
  uint16_t* xb  = (uint16_t*)(ws);
  uint16_t* xtb = (uint16_t*)(ws + (4u  << 20));
  float*    num = (float*)   (ws + (8u  << 20));
  float*    cs  = (float*)   (ws + (16u << 20));

  dim3 cgrid(NPTS/64, DFEAT/64);
  ms_combine<<<cgrid, 256, 0, stream>>>(X, nullptr, nullptr, xb, xtb, 0);
  for (int it = 0; it < 3; ++it) {
    hipMemsetAsync(ws + (8u << 20), 0, (8u << 20) + NPTS*4, stream);
    ms_fused<<<512, 256, 0, stream>>>(xb, xtb, num, cs);
    ms_combine<<<cgrid, 256, 0, stream>>>(num, cs, out + (size_t)it*DFEAT*NPTS,
                                          xb, xtb, 1);
  }
}

// Round 3
// 570.629 us; speedup vs baseline: 1.0629x; 1.0629x over previous
//
#include <hip/hip_runtime.h>
#include <hip/hip_bf16.h>
#include <stdint.h>

#define DFEAT 256
#define NPTS  8192

typedef __attribute__((ext_vector_type(8)))  short bf16x8;   // 8 bf16 = 4 VGPRs
typedef __attribute__((ext_vector_type(16))) float f32x16;   // 32x32 C/D
typedef __attribute__((ext_vector_type(4)))  int   int4v;

__device__ inline uint16_t f2bf(float f) {  // RNE fp32->bf16
  union { float f; uint32_t u; } v; v.f = f;
  return (uint16_t)((v.u + 0x7FFFu + ((v.u >> 16) & 1u)) >> 16);
}

// ---------------------------------------------------------------------------
// ws fragment layouts (written by ms_combine):
//  xaf: per 32-point block nb, per 16B chunk s=2*ks+g, per lane 0..31:
//       X[d = s*8 .. +8][pt = nb*32+lane]  -> MFMA A/B-frag order, k=d.
//       addr = nb*16384 + s*512 + lane*16.          (4 MB)
//  xbf: per 32-d block db, per chunk u (n/8), per lane:
//       X[d = db*32+lane][n = u*8 .. +8]   -> PV A-frag order, k=n.
//       addr = db*524288 + u*512 + lane*16.         (4 MB)
// All hot-loop wave loads are 1KB contiguous.
// ---------------------------------------------------------------------------

// Fused mean-shift step. Per WG: m-tile 64, contiguous run of 64-pt n-tiles.
//   S[n,m] = Xn^T Xm (A from xaf, B resident regs)  -> P = exp(6S) -> LDS Ps
//   CS[m] += colsum(P) ; O[d,m] += Xn P (A from xbf, B from Ps)
// Only Ps lives in LDS (8 KB, XOR-swizzled chunks). 2 barriers/iter.
// grid = 128 m-tiles x 6 n-splits (22/22/21/21/21/21) = 768 = 3 WGs/CU.
__global__ __launch_bounds__(256, 3) void ms_fused(
    const uint16_t* __restrict__ xaf,
    const uint16_t* __restrict__ xbf,
    float* __restrict__ num,           // [256][8192] fp32, pre-zeroed
    float* __restrict__ cs)            // [8192] fp32, pre-zeroed
{
  // Ps: 64 m-rows x 128B; logical chunk c (rows n 8c..8c+7) at pos c^(m&7)
  __shared__ __attribute__((aligned(16))) uint16_t Ps[64 * 64];

  const int tid  = threadIdx.x;
  const int w    = tid >> 6;
  const int lane = tid & 63;
  const int l31  = lane & 31;
  const int g    = lane >> 5;
  const int bid  = blockIdx.x;
  const int mt   = bid & 127;
  const int sidx = bid >> 7;                 // n-split 0..5
  const int m0   = mt * 64;
  const int jstart = (sidx < 2) ? 22 * sidx : 44 + 21 * (sidx - 2);
  const int jcount = (sidx < 2) ? 22 : 21;
  const int a_sub = w >> 1;                  // S n-sub (0/1)
  const int b_sub = w & 1;                   // S m-sub (0/1)

  const char* xafc = (const char*)xaf;
  const char* xbfc = (const char*)xbf;
  char*       Psc  = (char*)Ps;

  // Xm B-fragments resident (64 VGPRs)
  bf16x8 Bm[16];
  {
    const char* bp = xafc + (size_t)(m0 / 32 + b_sub) * 16384 + g * 512 + l31 * 16;
    #pragma unroll
    for (int ks = 0; ks < 16; ++ks)
      Bm[ks] = __builtin_bit_cast(bf16x8, *(const int4v*)(bp + ks * 1024));
  }

  f32x16 accO[2][2];
  #pragma unroll
  for (int i = 0; i < 2; ++i)
    #pragma unroll
    for (int j = 0; j < 2; ++j)
      #pragma unroll
      for (int r = 0; r < 16; ++r) accO[i][j][r] = 0.0f;
  float csacc = 0.0f;

  const int mloc = 32 * b_sub + l31;
  const int l7   = l31 & 7;

  for (int t = 0; t < jcount; ++t) {
    const int n0 = (jstart + t) * 64;
    __syncthreads();  // Ps WAR

    // ---- S = Xn^T Xm : A-frags from xaf (coalesced 1KB wave loads) ----
    f32x16 s;
    #pragma unroll
    for (int r = 0; r < 16; ++r) s[r] = 0.0f;
    {
      const char* ap = xafc + (size_t)((n0 >> 5) + a_sub) * 16384 + g * 512 + l31 * 16;
      #pragma unroll
      for (int ks = 0; ks < 16; ++ks) {
        bf16x8 A = __builtin_bit_cast(bf16x8, *(const int4v*)(ap + ks * 1024));
        s = __builtin_amdgcn_mfma_f32_32x32x16_bf16(A, Bm[ks], s, 0, 0, 0);
      }
    }

    // ---- P = exp(6S); colsum; pack to Ps (4 ds_write_b64, swizzled) ----
    #pragma unroll
    for (int k = 0; k < 4; ++k) {
      float e0 = __expf(6.0f * s[4*k+0]);
      float e1 = __expf(6.0f * s[4*k+1]);
      float e2 = __expf(6.0f * s[4*k+2]);
      float e3 = __expf(6.0f * s[4*k+3]);
      csacc += (e0 + e1) + (e2 + e3);
      uint32_t lo = (uint32_t)f2bf(e0) | ((uint32_t)f2bf(e1) << 16);
      uint32_t hi = (uint32_t)f2bf(e2) | ((uint32_t)f2bf(e3) << 16);
      int p = (4 * a_sub + k) ^ (mloc & 7);
      *(uint64_t*)(Psc + mloc * 128 + p * 16 + 8 * g) =
          ((uint64_t)hi << 32) | lo;
    }

    // ---- prefetch PV A-frags (independent of Ps) ----
    bf16x8 Xf[2][4];
    #pragma unroll
    for (int t2 = 0; t2 < 2; ++t2) {
      const char* xp = xbfc + (size_t)(2 * w + t2) * 524288 +
                       (size_t)(n0 >> 3) * 512 + g * 512 + l31 * 16;
      #pragma unroll
      for (int ks = 0; ks < 4; ++ks)
        Xf[t2][ks] = __builtin_bit_cast(bf16x8, *(const int4v*)(xp + ks * 1024));
    }
    __syncthreads();  // Ps visible

    // ---- O[d,m] += Xn * P ----
    #pragma unroll
    for (int ks = 0; ks < 4; ++ks) {
      bf16x8 Bp[2];
      #pragma unroll
      for (int mm = 0; mm < 2; ++mm) {
        int mrow = 32 * mm + l31;
        int p = (2 * ks + g) ^ l7;
        Bp[mm] = __builtin_bit_cast(bf16x8,
            *(const int4v*)(Psc + mrow * 128 + p * 16));
      }
      #pragma unroll
      for (int t2 = 0; t2 < 2; ++t2) {
        accO[t2][0] = __builtin_amdgcn_mfma_f32_32x32x16_bf16(Xf[t2][ks], Bp[0], accO[t2][0], 0,0,0);
        accO[t2][1] = __builtin_amdgcn_mfma_f32_32x32x16_bf16(Xf[t2][ks], Bp[1], accO[t2][1], 0,0,0);
      }
    }
  }

  // ---- epilogue: merge partials ----
  csacc += __shfl_xor(csacc, 32, 64);
  if (g == 0) atomicAdd(&cs[m0 + mloc], csacc);
  #pragma unroll
  for (int t2 = 0; t2 < 2; ++t2)
    #pragma unroll
    for (int mm = 0; mm < 2; ++mm)
      #pragma unroll
      for (int r = 0; r < 16; ++r) {
        int drow = 32 * (2 * w + t2) + (r & 3) + 8 * (r >> 2) + 4 * g;
        int mg   = m0 + 32 * mm + l31;
        atomicAdd(&num[(size_t)drow * NPTS + mg], accO[t2][mm][r]);
      }
}

// ---------------------------------------------------------------------------
// Combine. mode1: v = num/cs -> yout; zero num after read; zero cs_next.
//          mode0: v = src (initial fp32 X). Both: emit xaf + xbf frags.
// ---------------------------------------------------------------------------
__global__ __launch_bounds__(256) void ms_combine(
    const float* __restrict__ src, const float* __restrict__ csr,
    float* __restrict__ csz, float* __restrict__ yout,
    float* __restrict__ numz,
    uint16_t* __restrict__ xaf, uint16_t* __restrict__ xbf,
    const int mode)
{
  __shared__ uint16_t T[64][66];
  const int tid = threadIdx.x;
  const int n0 = blockIdx.x * 64;
  const int d0 = blockIdx.y * 64;

  #pragma unroll
  for (int i = 0; i < 16; ++i) {
    int e  = tid + i * 256;
    int dl = e >> 6, nl = e & 63;
    size_t idx = (size_t)(d0 + dl) * NPTS + (n0 + nl);
    float v = src[idx];
    if (mode) { v /= csr[n0 + nl]; yout[idx] = v; numz[idx] = 0.0f; }
    T[dl][nl] = f2bf(v);
  }
  if (mode && blockIdx.y == 0 && tid < 64) csz[n0 + tid] = 0.0f;
  __syncthreads();

  char* xafc = (char*)xaf;
  char* xbfc = (char*)xbf;
  // xaf chunks: (nb, s, lane) -> T[s*8 + j][nb*32+lane]
  #pragma unroll
  for (int i = 0; i < 2; ++i) {
    int c  = tid + i * 256;
    int nb = c >> 8, s2 = (c >> 5) & 7, ln = c & 31;
    union { uint32_t u[4]; int4v v; } pk;
    #pragma unroll
    for (int k = 0; k < 4; ++k) {
      uint32_t lo = T[s2 * 8 + 2 * k][nb * 32 + ln];
      uint32_t hi = T[s2 * 8 + 2 * k + 1][nb * 32 + ln];
      pk.u[k] = lo | (hi << 16);
    }
    *(int4v*)(xafc + (size_t)(n0 / 32 + nb) * 16384 +
              (size_t)(d0 / 8 + s2) * 512 + ln * 16) = pk.v;
  }
  // xbf chunks: (db, u, lane) -> T[db*32+lane][u*8 + j]  (row-contiguous)
  #pragma unroll
  for (int i = 0; i < 2; ++i) {
    int c  = tid + i * 256;
    int db = c >> 8, uu = (c >> 5) & 7, ln = c & 31;
    const uint16_t* tr = &T[db * 32 + ln][uu * 8];
    union { uint32_t u[4]; int4v v; } pk;
    #pragma unroll
    for (int k = 0; k < 4; ++k)
      pk.u[k] = (uint32_t)tr[2 * k] | ((uint32_t)tr[2 * k + 1] << 16);
    *(int4v*)(xbfc + (size_t)(d0 / 32 + db) * 524288 +
              (size_t)(n0 / 8 + uu) * 512 + ln * 16) = pk.v;
  }
}

extern "C" void kernel_launch(void* const* d_in, const int* in_sizes, int n_in,
                              void* d_out, int out_size, void* d_ws, size_t ws_size,
                              hipStream_t stream)
{
  (void)in_sizes; (void)n_in; (void)out_size; (void)ws_size;
  const float* X = (const float*)d_in[0];
  float* out = (float*)d_out;
  char* ws = (char*)d_ws;
  // ws: [0,4M) xaf ; [4M,8M) xbf ; [8M,16M) num ; [16M,+32K) cs0 ; [+32K) cs1
  uint16_t* xaf = (uint16_t*)(ws);
  uint16_t* xbf = (uint16_t*)(ws + (4u << 20));
  float*    num = (float*)   (ws + (8u << 20));
  float*    cs0 = (float*)   (ws + (16u << 20));
  float*    cs1 = (float*)   (ws + (16u << 20) + 32768);

  // zero num + both cs buffers once per call (ws is re-poisoned each call)
  hipMemsetAsync(ws + (8u << 20), 0, (8u << 20) + 65536, stream);

  dim3 cgrid(NPTS / 64, DFEAT / 64);
  ms_combine<<<cgrid, 256, 0, stream>>>(X, nullptr, nullptr, nullptr, nullptr,
                                        xaf, xbf, 0);
  for (int it = 0; it < 3; ++it) {
    float* csA = (it & 1) ? cs1 : cs0;
    float* csB = (it & 1) ? cs0 : cs1;
    ms_fused<<<768, 256, 0, stream>>>(xaf, xbf, num, csA);
    ms_combine<<<cgrid, 256, 0, stream>>>(num, csA, csB,
                                          out + (size_t)it * DFEAT * NPTS,
                                          num, xaf, xbf, 1);
  }
}

// Round 4
// 349.001 us; speedup vs baseline: 1.7380x; 1.6350x over previous
//
#include <hip/hip_runtime.h>
#include <hip/hip_bf16.h>
#include <stdint.h>

#define DFEAT 256
#define NPTS  8192

typedef __attribute__((ext_vector_type(8)))  short bf16x8;   // 8 bf16 = 4 VGPRs
typedef __attribute__((ext_vector_type(16))) float f32x16;   // 32x32 C/D
typedef __attribute__((ext_vector_type(4)))  int   int4v;
typedef __attribute__((ext_vector_type(4)))  float f32x4;

#define AS1 __attribute__((address_space(1)))
#define AS3 __attribute__((address_space(3)))

__device__ inline void dma16(const void* g, void* l) {
  // async global->LDS, 16B/lane; LDS dest = wave-uniform base + lane*16
  __builtin_amdgcn_global_load_lds((const AS1 uint32_t*)g, (AS3 uint32_t*)l, 16, 0, 0);
}

__device__ inline uint16_t f2bf(float f) {  // RNE fp32->bf16
  union { float f; uint32_t u; } v; v.f = f;
  return (uint16_t)((v.u + 0x7FFFu + ((v.u >> 16) & 1u)) >> 16);
}

// ---------------------------------------------------------------------------
// ws fragment layouts (written by ms_combine):
//  xaf: per 32-point block nb, chunk s=2*ks+g, lane 0..31:
//       X[d = s*8 .. +8][pt = nb*32+lane]  (A/B-frag order, k=d)
//       byte addr = nb*16384 + s*512 + lane*16.     (4 MB)
//  xbf: per 32-d block db, chunk u (n/8), lane:
//       X[d = db*32+lane][n = u*8 .. +8]   (PV A-frag order, k=n)
//       byte addr = db*524288 + u*512 + lane*16.    (4 MB)
// xaf's n-tile slice [j*32768, +32768) is DMA'd to LDS as an IDENTITY copy:
// lane-major inner layout -> wave-contiguous DMA and conflict-free ds_reads.
// ---------------------------------------------------------------------------

// Fused mean-shift step. Per WG: m-tile 64, 32 consecutive n-tiles of 64.
//   S[n,m] = Xn^T Xm (A from double-buffered LDS stage, B resident regs)
//   P = exp(6S) -> LDS Ps ; CS[m] += colsum ; O[d,m] += Xn P (A from xbf regs)
// DMA(t+1) issued right after top barrier -> flies across S(t) before the
// mid-barrier vmcnt drain. grid = 128 m-tiles x 4 n-splits = 512 = 2 WG/CU.
__global__ __launch_bounds__(256, 2) void ms_fused(
    const uint16_t* __restrict__ xaf,
    const uint16_t* __restrict__ xbf,
    float* __restrict__ num,           // [256][8192] fp32, pre-zeroed
    float* __restrict__ cs)            // [8192] fp32, pre-zeroed
{
  __shared__ __attribute__((aligned(16))) uint16_t XT[2][16384];  // 2x32KB stage
  __shared__ __attribute__((aligned(16))) uint16_t Ps[64 * 64];   // 8KB swizzled

  const int tid  = threadIdx.x;
  const int w    = tid >> 6;
  const int lane = tid & 63;
  const int l31  = lane & 31;
  const int g    = lane >> 5;
  const int mt   = blockIdx.x & 127;
  const int q    = blockIdx.x >> 7;          // n-split 0..3
  const int m0   = mt * 64;
  const int a_sub = w >> 1;                  // S n-sub (0/1)
  const int b_sub = w & 1;                   // S m-sub (0/1)

  const char* xafc = (const char*)xaf;
  const char* xbfc = (const char*)xbf;
  char*       Psc  = (char*)Ps;

  // Xm B-fragments resident (64 VGPRs), one-time coalesced load
  bf16x8 Bm[16];
  {
    const char* bp = xafc + (size_t)(m0 / 32 + b_sub) * 16384 + g * 512 + l31 * 16;
    #pragma unroll
    for (int ks = 0; ks < 16; ++ks)
      Bm[ks] = __builtin_bit_cast(bf16x8, *(const int4v*)(bp + ks * 1024));
  }

  f32x16 accO[2][2];
  #pragma unroll
  for (int i = 0; i < 2; ++i)
    #pragma unroll
    for (int j = 0; j < 2; ++j)
      #pragma unroll
      for (int r = 0; r < 16; ++r) accO[i][j][r] = 0.0f;
  float csacc = 0.0f;

  const int mloc = 32 * b_sub + l31;
  const int l7   = l31 & 7;
  const int j0   = q * 32;                   // first n-tile index

  // prologue: stage tile j0 into buf 0 (identity copy, 8x 16B per thread)
  {
    const char* src = xafc + (size_t)j0 * 32768;
    #pragma unroll
    for (int r = 0; r < 8; ++r)
      dma16(src + tid * 16 + r * 4096, (char*)XT[0] + tid * 16 + r * 4096);
  }

  for (int t = 0; t < 32; ++t) {
    const int jt  = j0 + t;
    const int cur = t & 1;
    __syncthreads();  // A: DMA(t) drained into XT[cur]; Ps writable (PV(t-1) done)

    // issue DMA(t+1) -> other buffer; flies across the whole S phase
    if (t < 31) {
      const char* src = xafc + (size_t)(jt + 1) * 32768;
      #pragma unroll
      for (int r = 0; r < 8; ++r)
        dma16(src + tid * 16 + r * 4096,
              (char*)XT[cur ^ 1] + tid * 16 + r * 4096);
    }

    // prefetch PV A-frags from global (coalesced 1KB wave loads, 32 VGPRs)
    const int n0 = jt * 64;
    bf16x8 Xf[2][4];
    #pragma unroll
    for (int t2 = 0; t2 < 2; ++t2) {
      const char* xp = xbfc + (size_t)(2 * w + t2) * 524288 +
                       (size_t)(n0 >> 3) * 512 + g * 512 + l31 * 16;
      #pragma unroll
      for (int ks = 0; ks < 4; ++ks)
        Xf[t2][ks] = __builtin_bit_cast(bf16x8, *(const int4v*)(xp + ks * 1024));
    }

    // ---- S = Xn^T Xm : A-frags from staged LDS (conflict-free b128) ----
    f32x16 s;
    #pragma unroll
    for (int r = 0; r < 16; ++r) s[r] = 0.0f;
    {
      const char* ap = (const char*)XT[cur] + a_sub * 16384 + g * 512 + l31 * 16;
      #pragma unroll
      for (int ks = 0; ks < 16; ++ks) {
        bf16x8 A = __builtin_bit_cast(bf16x8, *(const int4v*)(ap + ks * 1024));
        s = __builtin_amdgcn_mfma_f32_32x32x16_bf16(A, Bm[ks], s, 0, 0, 0);
      }
    }

    // ---- P = exp(6S); colsum; pack to Ps (4 ds_write_b64, swizzled) ----
    #pragma unroll
    for (int k = 0; k < 4; ++k) {
      float e0 = __expf(6.0f * s[4*k+0]);
      float e1 = __expf(6.0f * s[4*k+1]);
      float e2 = __expf(6.0f * s[4*k+2]);
      float e3 = __expf(6.0f * s[4*k+3]);
      csacc += (e0 + e1) + (e2 + e3);
      uint32_t lo = (uint32_t)f2bf(e0) | ((uint32_t)f2bf(e1) << 16);
      uint32_t hi = (uint32_t)f2bf(e2) | ((uint32_t)f2bf(e3) << 16);
      int p = (4 * a_sub + k) ^ (mloc & 7);
      *(uint64_t*)(Psc + mloc * 128 + p * 16 + 8 * g) =
          ((uint64_t)hi << 32) | lo;
    }
    __syncthreads();  // B: Ps visible (also drains DMA(t+1)/Xf after ~S-phase)

    // ---- O[d,m] += Xn * P ----
    #pragma unroll
    for (int ks = 0; ks < 4; ++ks) {
      bf16x8 Bp[2];
      #pragma unroll
      for (int mm = 0; mm < 2; ++mm) {
        int mrow = 32 * mm + l31;
        int p = (2 * ks + g) ^ l7;
        Bp[mm] = __builtin_bit_cast(bf16x8,
            *(const int4v*)(Psc + mrow * 128 + p * 16));
      }
      #pragma unroll
      for (int t2 = 0; t2 < 2; ++t2) {
        accO[t2][0] = __builtin_amdgcn_mfma_f32_32x32x16_bf16(Xf[t2][ks], Bp[0], accO[t2][0], 0,0,0);
        accO[t2][1] = __builtin_amdgcn_mfma_f32_32x32x16_bf16(Xf[t2][ks], Bp[1], accO[t2][1], 0,0,0);
      }
    }
  }

  // ---- epilogue: merge partials ----
  csacc += __shfl_xor(csacc, 32, 64);
  if (g == 0) atomicAdd(&cs[m0 + mloc], csacc);
  #pragma unroll
  for (int t2 = 0; t2 < 2; ++t2)
    #pragma unroll
    for (int mm = 0; mm < 2; ++mm)
      #pragma unroll
      for (int r = 0; r < 16; ++r) {
        int drow = 32 * (2 * w + t2) + (r & 3) + 8 * (r >> 2) + 4 * g;
        int mg   = m0 + 32 * mm + l31;
        atomicAdd(&num[(size_t)drow * NPTS + mg], accO[t2][mm][r]);
      }
}

// ---------------------------------------------------------------------------
// Combine. mode1: v = num/cs -> yout; zero num after read; zero cs_next.
//          mode0: v = src (initial fp32 X). Both: emit xaf + xbf frags.
// float4-vectorized global traffic.
// ---------------------------------------------------------------------------
__global__ __launch_bounds__(256) void ms_combine(
    const float* __restrict__ src, const float* __restrict__ csr,
    float* __restrict__ csz, float* __restrict__ yout,
    float* __restrict__ numz,
    uint16_t* __restrict__ xaf, uint16_t* __restrict__ xbf,
    const int mode)
{
  __shared__ uint16_t T[64][66];
  const int tid = threadIdx.x;
  const int n0 = blockIdx.x * 64;
  const int d0 = blockIdx.y * 64;

  #pragma unroll
  for (int i = 0; i < 4; ++i) {
    int e  = tid + i * 256;              // float4 slot
    int dl = e >> 4, nq = e & 15;
    size_t idx = (size_t)(d0 + dl) * NPTS + (n0 + nq * 4);
    f32x4 v = *(const f32x4*)(src + idx);
    if (mode) {
      f32x4 c = *(const f32x4*)(csr + n0 + nq * 4);
      v /= c;
      *(f32x4*)(yout + idx) = v;
      f32x4 z = {0.f, 0.f, 0.f, 0.f};
      *(f32x4*)(numz + idx) = z;
    }
    #pragma unroll
    for (int k = 0; k < 4; ++k) T[dl][nq * 4 + k] = f2bf(v[k]);
  }
  if (mode && blockIdx.y == 0 && tid < 64) csz[n0 + tid] = 0.0f;
  __syncthreads();

  char* xafc = (char*)xaf;
  char* xbfc = (char*)xbf;
  // xaf chunks: (nb, s, lane) -> T[s*8 + j][nb*32+lane]
  #pragma unroll
  for (int i = 0; i < 2; ++i) {
    int c  = tid + i * 256;
    int nb = c >> 8, s2 = (c >> 5) & 7, ln = c & 31;
    union { uint32_t u[4]; int4v v; } pk;
    #pragma unroll
    for (int k = 0; k < 4; ++k) {
      uint32_t lo = T[s2 * 8 + 2 * k][nb * 32 + ln];
      uint32_t hi = T[s2 * 8 + 2 * k + 1][nb * 32 + ln];
      pk.u[k] = lo | (hi << 16);
    }
    *(int4v*)(xafc + (size_t)(n0 / 32 + nb) * 16384 +
              (size_t)(d0 / 8 + s2) * 512 + ln * 16) = pk.v;
  }
  // xbf chunks: (db, u, lane) -> T[db*32+lane][u*8 + j]  (row-contiguous)
  #pragma unroll
  for (int i = 0; i < 2; ++i) {
    int c  = tid + i * 256;
    int db = c >> 8, uu = (c >> 5) & 7, ln = c & 31;
    const uint16_t* tr = &T[db * 32 + ln][uu * 8];
    union { uint32_t u[4]; int4v v; } pk;
    #pragma unroll
    for (int k = 0; k < 4; ++k)
      pk.u[k] = (uint32_t)tr[2 * k] | ((uint32_t)tr[2 * k + 1] << 16);
    *(int4v*)(xbfc + (size_t)(d0 / 32 + db) * 524288 +
              (size_t)(n0 / 8 + uu) * 512 + ln * 16) = pk.v;
  }
}

extern "C" void kernel_launch(void* const* d_in, const int* in_sizes, int n_in,
                              void* d_out, int out_size, void* d_ws, size_t ws_size,
                              hipStream_t stream)
{
  (void)in_sizes; (void)n_in; (void)out_size; (void)ws_size;
  const float* X = (const float*)d_in[0];
  float* out = (float*)d_out;
  char* ws = (char*)d_ws;
  // ws: [0,4M) xaf ; [4M,8M) xbf ; [8M,16M) num ; [16M,+32K) cs0 ; [+32K) cs1
  uint16_t* xaf = (uint16_t*)(ws);
  uint16_t* xbf = (uint16_t*)(ws + (4u << 20));
  float*    num = (float*)   (ws + (8u << 20));
  float*    cs0 = (float*)   (ws + (16u << 20));
  float*    cs1 = (float*)   (ws + (16u << 20) + 32768);

  // zero num + both cs buffers once per call (ws is re-poisoned each call)
  hipMemsetAsync(ws + (8u << 20), 0, (8u << 20) + 65536, stream);

  dim3 cgrid(NPTS / 64, DFEAT / 64);
  ms_combine<<<cgrid, 256, 0, stream>>>(X, nullptr, nullptr, nullptr, nullptr,
                                        xaf, xbf, 0);
  for (int it = 0; it < 3; ++it) {
    float* csA = (it & 1) ? cs1 : cs0;
    float* csB = (it & 1) ? cs0 : cs1;
    ms_fused<<<512, 256, 0, stream>>>(xaf, xbf, num, csA);
    ms_combine<<<cgrid, 256, 0, stream>>>(num, csA, csB,
                                          out + (size_t)it * DFEAT * NPTS,
                                          num, xaf, xbf, 1);
  }
}